// Round 6
// baseline (232.610 us; speedup 1.0000x reference)
//
#include <hip/hip_runtime.h>
#include <math.h>

#define B_PAIRS 4096
#define NNODES  64
#define NEDGES  256
#define FDIM    128
#define HDIM    64
#define FPDIM   2048
#define MDIM    256
#define KTOT    4224   // 2*HDIM + 2*FPDIM

typedef __attribute__((ext_vector_type(4))) float f32x4;
typedef __bf16 bf16x8 __attribute__((ext_vector_type(8)));

__device__ __forceinline__ unsigned short f2bf(float f) {
    return __builtin_bit_cast(unsigned short, (__bf16)f);
}
__device__ __forceinline__ unsigned pack2(float a, float b) {
    return (unsigned)f2bf(a) | ((unsigned)f2bf(b) << 16);
}

// ---------------------------------------------------------------------------
// Kernel 0a: W1t[n][k]=W1[k][n], W2t[n][k]=W2[k][n] (bf16), grid-strided.
// ---------------------------------------------------------------------------
__global__ void prep_weights(const float* __restrict__ W1, const float* __restrict__ W2,
                             unsigned short* __restrict__ W1t, unsigned short* __restrict__ W2t) {
    const int t0 = blockIdx.x * 256 + threadIdx.x;
    const int stride = gridDim.x * 256;
    for (int i = t0; i < HDIM * FDIM; i += stride) {
        const int n = i >> 7, k = i & 127;
        W1t[i] = f2bf(W1[k * HDIM + n]);
    }
    for (int i = t0; i < HDIM * HDIM; i += stride) {
        const int n = i >> 6, k = i & 63;
        W2t[i] = f2bf(W2[k * HDIM + n]);
    }
}

// ---------------------------------------------------------------------------
// Kernel 0b: Wm1t[n][k] = bf16(Wm1[k][n]), n<256, k<4224. Tiled 32x32 via LDS.
// ---------------------------------------------------------------------------
__global__ __launch_bounds__(256)
void prep_wm1(const float* __restrict__ Wm1, unsigned short* __restrict__ Wm1t) {
    __shared__ float tile[32][33];
    const int k0 = blockIdx.x * 32, n0 = blockIdx.y * 32;
    const int t = threadIdx.x;
    const int c = t & 31, r8 = t >> 5;
    #pragma unroll
    for (int rr = r8; rr < 32; rr += 8)
        tile[rr][c] = Wm1[(size_t)(k0 + rr) * MDIM + n0 + c];
    __syncthreads();
    #pragma unroll
    for (int j = 0; j < 4; ++j) {
        const int n = n0 + r8 + 8 * j;
        Wm1t[(size_t)n * KTOT + k0 + c] = f2bf(tile[c][r8 + 8 * j]);
    }
}

// ---------------------------------------------------------------------------
// Kernel 1: per-graph GCN encoder, all-MFMA.
// X A-fragments loaded straight to registers (no Xb staging). LDS 28160 B
// -> 5 blocks/CU (20 waves/CU). Layout (bytes):
//   [    0, 8192)  Ab bf16[64][64] swizzled (live whole kernel)
//   [ 8192,16640)  cnt32 u32[64][33] until B2; then T1t bf16[64][64] at
//                  [8192,16384) (step1->step2); then T3t same region (step3->4)
//   [16640,24832)  T2b bf16[64][64] (step2->step3)
//   [24832,28160)  srcs/dsts/deg/pool
// ---------------------------------------------------------------------------
__global__ __launch_bounds__(256, 5)
void encode_kernel(const float* __restrict__ x1, const float* __restrict__ x2,
                   const int* __restrict__ e1, const int* __restrict__ e2,
                   const unsigned short* __restrict__ W1t, const float* __restrict__ b1,
                   const unsigned short* __restrict__ W2t, const float* __restrict__ b2,
                   float* __restrict__ hbuf) {
    __shared__ __align__(16) unsigned char lds[28160];
    const int gid  = blockIdx.x;
    const int drug = gid >> 12;
    const int b    = gid & (B_PAIRS - 1);
    const float* x  = (drug ? x2 : x1) + (size_t)b * NNODES * FDIM;
    const int*   eg = (drug ? e2 : e1) + (size_t)b * 2 * NEDGES;

    const int t    = threadIdx.x;
    const int lane = t & 63, wid = t >> 6;
    const int lr   = lane & 15, lg = lane >> 4;
    const int mt   = wid;
    const int m0   = 16 * mt + 4 * lg;

    unsigned* cnt32 = (unsigned*)(lds + 8192);    // u32[64][33]
    int*   srcs = (int*)(lds + 24832);
    int*   dsts = (int*)(lds + 25856);
    int*   deg  = (int*)(lds + 26880);
    float* pool = (float*)(lds + 27136);

    // fire this lane's step-1 A-fragment loads immediately (X row 16mt+lr)
    float4 xa[8];
    {
        const float* xrow = x + (size_t)(16 * mt + lr) * FDIM + 8 * lg;
        #pragma unroll
        for (int ks = 0; ks < 4; ++ks) {
            xa[2 * ks]     = ((const float4*)(xrow + 32 * ks))[0];
            xa[2 * ks + 1] = ((const float4*)(xrow + 32 * ks))[1];
        }
    }

    // zero cnt32 (2112 u32 = 528 uint4), load edges, zero deg
    for (int i = t; i < 528; i += 256) ((uint4*)cnt32)[i] = make_uint4(0, 0, 0, 0);
    { srcs[t] = eg[t]; dsts[t] = eg[NEDGES + t]; }
    if (t < NNODES) deg[t] = 0;
    __syncthreads();                                           // B0
    {
        const int d = dsts[t], s = srcs[t];
        atomicAdd(&deg[d], 1);
        atomicAdd(&cnt32[d * 33 + (s >> 1)], 1u << ((s & 1) * 16));
    }
    __syncthreads();                                           // B1

    // build A-hat bf16 swizzled at base 0
    {
        const int r = t >> 2, c0 = (t & 3) << 4;
        const float dr = rsqrtf((float)deg[r] + 1.0f);
        unsigned char* arow = lds + r * 128;
        const unsigned sw = (r & 7) << 4;
        #pragma unroll
        for (int j = 0; j < 16; j += 2) {
            const int c = c0 + j;                    // even
            const unsigned w = cnt32[r * 33 + (c >> 1)];
            const float n0 = (float)((w & 0xffffu) + (r == c     ? 1u : 0u));
            const float n1 = (float)((w >> 16)     + (r == c + 1 ? 1u : 0u));
            const float v0 = n0 * dr * rsqrtf((float)deg[c]     + 1.0f);
            const float v1 = n1 * dr * rsqrtf((float)deg[c + 1] + 1.0f);
            *(unsigned*)(arow + (((unsigned)(2 * c)) ^ sw)) = pack2(v0, v1);
        }
    }
    __syncthreads();                                           // B2 (cnt32 dead)

    // step1: T1 = X @ W1 (A from registers) -> T1t[featH][node] at 8192
    {
        f32x4 acc[4];
        #pragma unroll
        for (int nt = 0; nt < 4; ++nt) acc[nt] = (f32x4){0.f, 0.f, 0.f, 0.f};
        #pragma unroll
        for (int ks = 0; ks < 4; ++ks) {
            bf16x8 a;
            const float4 u = xa[2 * ks], v = xa[2 * ks + 1];
            a[0] = (__bf16)u.x; a[1] = (__bf16)u.y; a[2] = (__bf16)u.z; a[3] = (__bf16)u.w;
            a[4] = (__bf16)v.x; a[5] = (__bf16)v.y; a[6] = (__bf16)v.z; a[7] = (__bf16)v.w;
            #pragma unroll
            for (int nt = 0; nt < 4; ++nt) {
                const bf16x8 bw = *(const bf16x8*)(W1t + (16 * nt + lr) * 128 + 32 * ks + 8 * lg);
                acc[nt] = __builtin_amdgcn_mfma_f32_16x16x32_bf16(a, bw, acc[nt], 0, 0, 0);
            }
        }
        #pragma unroll
        for (int nt = 0; nt < 4; ++nt) {
            const int f = 16 * nt + lr;
            const unsigned lo = pack2(acc[nt][0], acc[nt][1]);
            const unsigned hi = pack2(acc[nt][2], acc[nt][3]);
            const unsigned off = 8192u + (unsigned)f * 128 + (((unsigned)(2 * m0)) ^ ((unsigned)(f & 7) << 4));
            *(unsigned long long*)(lds + off) = (unsigned long long)lo | ((unsigned long long)hi << 32);
        }
    }
    __syncthreads();                                           // B3

    // step2: T2^T = T1t @ A^T (+b1, relu) -> T2b[node][featH] at 16640
    {
        f32x4 acc[4];
        #pragma unroll
        for (int nt = 0; nt < 4; ++nt) acc[nt] = (f32x4){0.f, 0.f, 0.f, 0.f};
        const int ar = 16 * mt + lr;
        const unsigned asw = (unsigned)(ar & 7) << 4;
        #pragma unroll
        for (int ks = 0; ks < 2; ++ks) {
            const unsigned kb = 64 * ks + 16 * lg;
            const bf16x8 a = *(const bf16x8*)(lds + 8192u + (unsigned)ar * 128 + (kb ^ asw));
            #pragma unroll
            for (int nt = 0; nt < 4; ++nt) {
                const int d = 16 * nt + lr;
                const bf16x8 bw = *(const bf16x8*)(lds + (unsigned)d * 128 + (kb ^ ((unsigned)(d & 7) << 4)));
                acc[nt] = __builtin_amdgcn_mfma_f32_16x16x32_bf16(a, bw, acc[nt], 0, 0, 0);
            }
        }
        const float4 b1v = *(const float4*)(b1 + m0);
        #pragma unroll
        for (int nt = 0; nt < 4; ++nt) {
            const int d = 16 * nt + lr;
            const float v0 = fmaxf(acc[nt][0] + b1v.x, 0.f);
            const float v1 = fmaxf(acc[nt][1] + b1v.y, 0.f);
            const float v2 = fmaxf(acc[nt][2] + b1v.z, 0.f);
            const float v3 = fmaxf(acc[nt][3] + b1v.w, 0.f);
            const unsigned off = 16640u + (unsigned)d * 128 + (((unsigned)(2 * m0)) ^ ((unsigned)(d & 7) << 4));
            *(unsigned long long*)(lds + off) =
                (unsigned long long)pack2(v0, v1) | ((unsigned long long)pack2(v2, v3) << 32);
        }
    }
    __syncthreads();                                           // B4 (T1t dead)

    // step3: T3 = T2b @ W2 -> T3t[outH][node] at 8192
    {
        f32x4 acc[4];
        #pragma unroll
        for (int nt = 0; nt < 4; ++nt) acc[nt] = (f32x4){0.f, 0.f, 0.f, 0.f};
        const int ar = 16 * mt + lr;
        const unsigned asw = (unsigned)(ar & 7) << 4;
        #pragma unroll
        for (int ks = 0; ks < 2; ++ks) {
            const unsigned kb = 64 * ks + 16 * lg;
            const bf16x8 a = *(const bf16x8*)(lds + 16640u + (unsigned)ar * 128 + (kb ^ asw));
            #pragma unroll
            for (int nt = 0; nt < 4; ++nt) {
                const bf16x8 bw = *(const bf16x8*)(W2t + (16 * nt + lr) * 64 + 32 * ks + 8 * lg);
                acc[nt] = __builtin_amdgcn_mfma_f32_16x16x32_bf16(a, bw, acc[nt], 0, 0, 0);
            }
        }
        #pragma unroll
        for (int nt = 0; nt < 4; ++nt) {
            const int n = 16 * nt + lr;
            const unsigned lo = pack2(acc[nt][0], acc[nt][1]);
            const unsigned hi = pack2(acc[nt][2], acc[nt][3]);
            const unsigned off = 8192u + (unsigned)n * 128 + (((unsigned)(2 * m0)) ^ ((unsigned)(n & 7) << 4));
            *(unsigned long long*)(lds + off) = (unsigned long long)lo | ((unsigned long long)hi << 32);
        }
    }
    __syncthreads();                                           // B5

    // step4: h2 = Ab @ T3 (+b2, relu) -> pool
    {
        f32x4 acc[4];
        #pragma unroll
        for (int nt = 0; nt < 4; ++nt) acc[nt] = (f32x4){0.f, 0.f, 0.f, 0.f};
        const int ar = 16 * mt + lr;
        const unsigned asw = (unsigned)(ar & 7) << 4;
        #pragma unroll
        for (int ks = 0; ks < 2; ++ks) {
            const unsigned kb = 64 * ks + 16 * lg;
            const bf16x8 a = *(const bf16x8*)(lds + (unsigned)ar * 128 + (kb ^ asw));
            #pragma unroll
            for (int nt = 0; nt < 4; ++nt) {
                const int n = 16 * nt + lr;
                const bf16x8 bw = *(const bf16x8*)(lds + 8192u + (unsigned)n * 128 + (kb ^ ((unsigned)(n & 7) << 4)));
                acc[nt] = __builtin_amdgcn_mfma_f32_16x16x32_bf16(a, bw, acc[nt], 0, 0, 0);
            }
        }
        float p[4];
        #pragma unroll
        for (int nt = 0; nt < 4; ++nt) {
            const float bb = b2[16 * nt + lr];
            float s = 0.f;
            #pragma unroll
            for (int r = 0; r < 4; ++r) s += fmaxf(acc[nt][r] + bb, 0.f);
            p[nt] = s;
        }
        #pragma unroll
        for (int nt = 0; nt < 4; ++nt) {
            p[nt] += __shfl_xor(p[nt], 16, 64);
            p[nt] += __shfl_xor(p[nt], 32, 64);
        }
        if (lg == 0) {
            #pragma unroll
            for (int nt = 0; nt < 4; ++nt) pool[wid * 64 + 16 * nt + lr] = p[nt];
        }
    }
    __syncthreads();                                           // B6
    if (t < HDIM) {
        const float s = pool[t] + pool[64 + t] + pool[128 + t] + pool[192 + t];
        hbuf[((size_t)drug * B_PAIRS + b) * HDIM + t] = s * (1.0f / 64.0f);
    }
}

// ---------------------------------------------------------------------------
// Kernel 2: fused MLP. hidden = relu([h1|h2|fp1|fp2] @ Wm1 + bm1);
//           out = sigmoid(hidden . Wm2 + bm2).  M=4096, N=256, K=4224.
// 512 threads = 8 waves (each wave owns 32 N-cols); 16 pairs/block; 256
// blocks. Double-buffered A tile (2x4KB); loads issued before the barrier.
// ---------------------------------------------------------------------------
__global__ __launch_bounds__(512)
void fused_mlp_kernel(const float* __restrict__ fp1, const float* __restrict__ fp2,
                      const float* __restrict__ hbuf,
                      const unsigned short* __restrict__ Wm1t,  // [256][4224] bf16
                      const float* __restrict__ bm1, const float* __restrict__ Wm2,
                      const float* __restrict__ bm2, float* __restrict__ out) {
    __shared__ __align__(16) unsigned char lds[8704];
    float* pool = (float*)(lds + 8192);            // 128 floats
    const int t = threadIdx.x;
    const int lane = t & 63, wid = t >> 6;         // wid 0..7
    const int lr = lane & 15, lg = lane >> 4;
    const int pair0 = blockIdx.x * 16;

    const int r  = t >> 5;                         // staging pair row 0..15
    const int kc = (t & 31) << 2;                  // staging k-offset (floats)
    const int pr = pair0 + r;
    const unsigned wOff = (unsigned)r * 256 + (((unsigned)(2 * kc)) ^ ((unsigned)(r & 7) << 4));

    f32x4 acc[2];
    acc[0] = (f32x4){0.f, 0.f, 0.f, 0.f};
    acc[1] = (f32x4){0.f, 0.f, 0.f, 0.f};

    const unsigned short* brow[2];
    #pragma unroll
    for (int nf = 0; nf < 2; ++nf)
        brow[nf] = Wm1t + (size_t)(32 * wid + 16 * nf + lr) * KTOT + 8 * lg;

    float4 va;
    #define LOAD_A(s)                                                                  \
        {                                                                              \
            const float* src;                                                          \
            if ((s) == 0)                                                              \
                src = (kc < 64) ? hbuf + (size_t)pr * HDIM + kc                        \
                                : hbuf + (size_t)(B_PAIRS + pr) * HDIM + (kc - 64);    \
            else if ((s) <= 16)                                                        \
                src = fp1 + (size_t)pr * FPDIM + ((s) - 1) * 128 + kc;                 \
            else                                                                       \
                src = fp2 + (size_t)pr * FPDIM + ((s) - 17) * 128 + kc;                \
            va = ((const float4*)src)[0];                                              \
        }
    #define STORE_A(base)                                                              \
        *(uint2*)((base) + wOff) = make_uint2(pack2(va.x, va.y), pack2(va.z, va.w));

    LOAD_A(0);
    STORE_A(lds);
    for (int s = 0; s < 33; ++s) {
        const bool more = (s + 1 < 33);
        if (more) LOAD_A(s + 1);                   // issue next-step globals early
        __syncthreads();                           // buf[s&1] ready; prev reads drained
        const unsigned char* buf = lds + (unsigned)((s & 1) << 12);
        const unsigned asw = (unsigned)(lr & 7) << 4;
        const int kglob = s << 7;
        #pragma unroll
        for (int ks = 0; ks < 4; ++ks) {
            const unsigned kb = (unsigned)(64 * ks + 16 * lg);
            const bf16x8 a = *(const bf16x8*)(buf + (unsigned)lr * 256 + (kb ^ asw));
            #pragma unroll
            for (int nf = 0; nf < 2; ++nf) {
                const bf16x8 bw = *(const bf16x8*)(brow[nf] + kglob + 32 * ks);
                acc[nf] = __builtin_amdgcn_mfma_f32_16x16x32_bf16(a, bw, acc[nf], 0, 0, 0);
            }
        }
        if (more) STORE_A(lds + (unsigned)(((s + 1) & 1) << 12));
    }

    // epilogue: bias, relu, dot Wm2, reduce over n, sigmoid
    float bm1v[2], wm2v[2];
    #pragma unroll
    for (int nf = 0; nf < 2; ++nf) {
        const int n = 32 * wid + 16 * nf + lr;
        bm1v[nf] = bm1[n];
        wm2v[nf] = Wm2[n];
    }
    #pragma unroll
    for (int reg = 0; reg < 4; ++reg) {            // row m = 4*lg + reg
        float p = 0.f;
        #pragma unroll
        for (int nf = 0; nf < 2; ++nf)
            p += fmaxf(acc[nf][reg] + bm1v[nf], 0.f) * wm2v[nf];
        p += __shfl_xor(p, 1, 64);
        p += __shfl_xor(p, 2, 64);
        p += __shfl_xor(p, 4, 64);
        p += __shfl_xor(p, 8, 64);
        if (lr == 0) pool[wid * 16 + 4 * lg + reg] = p;
    }
    __syncthreads();
    if (t < 16) {
        float y = bm2[0];
        #pragma unroll
        for (int w = 0; w < 8; ++w) y += pool[w * 16 + t];
        out[pair0 + t] = 1.0f / (1.0f + expf(-y));
    }
    #undef LOAD_A
    #undef STORE_A
}

extern "C" void kernel_launch(void* const* d_in, const int* in_sizes, int n_in,
                              void* d_out, int out_size, void* d_ws, size_t ws_size,
                              hipStream_t stream) {
    const float* x1  = (const float*)d_in[0];
    const float* x2  = (const float*)d_in[1];
    const int*   e1  = (const int*)d_in[2];
    const int*   e2  = (const int*)d_in[3];
    const float* fp1 = (const float*)d_in[4];
    const float* fp2 = (const float*)d_in[5];
    const float* W1  = (const float*)d_in[6];
    const float* b1  = (const float*)d_in[7];
    const float* W2  = (const float*)d_in[8];
    const float* b2  = (const float*)d_in[9];
    const float* Wm1 = (const float*)d_in[10];
    const float* bm1 = (const float*)d_in[11];
    const float* Wm2 = (const float*)d_in[12];
    const float* bm2 = (const float*)d_in[13];
    float* out  = (float*)d_out;

    float* hbuf = (float*)d_ws;                                          // 2 MB
    unsigned short* W1t  = (unsigned short*)((char*)d_ws + (2 << 20));   // 16 KB
    unsigned short* W2t  = W1t + HDIM * FDIM;                            // 8 KB
    unsigned short* Wm1t = (unsigned short*)((char*)d_ws + (3 << 20));   // 2.16 MB

    hipLaunchKernelGGL(prep_weights, dim3(16), dim3(256), 0, stream, W1, W2, W1t, W2t);
    hipLaunchKernelGGL(prep_wm1, dim3(132, 8), dim3(256), 0, stream, Wm1, Wm1t);
    hipLaunchKernelGGL(encode_kernel, dim3(2 * B_PAIRS), dim3(256), 0, stream,
                       x1, x2, e1, e2, W1t, b1, W2t, b2, hbuf);
    hipLaunchKernelGGL(fused_mlp_kernel, dim3(B_PAIRS / 16), dim3(512), 0, stream,
                       fp1, fp2, hbuf, Wm1t, bm1, Wm2, bm2, out);
}

// Round 7
// 170.128 us; speedup vs baseline: 1.3673x; 1.3673x over previous
//
#include <hip/hip_runtime.h>
#include <math.h>

#define B_PAIRS 4096
#define NNODES  64
#define NEDGES  256
#define FDIM    128
#define HDIM    64
#define FPDIM   2048
#define MDIM    256
#define KTOT    4224   // 2*HDIM + 2*FPDIM

typedef __attribute__((ext_vector_type(4))) float f32x4;
typedef __bf16 bf16x8 __attribute__((ext_vector_type(8)));

__device__ __forceinline__ unsigned short f2bf(float f) {
    return __builtin_bit_cast(unsigned short, (__bf16)f);
}
__device__ __forceinline__ unsigned pack2(float a, float b) {
    return (unsigned)f2bf(a) | ((unsigned)f2bf(b) << 16);
}
__device__ __forceinline__ unsigned long long pack4(float a, float b, float c, float d) {
    return (unsigned long long)pack2(a, b) | ((unsigned long long)pack2(c, d) << 32);
}

// ---------------------------------------------------------------------------
// Kernel 0a: W1t[n][k]=W1[k][n], W2t[n][k]=W2[k][n] (bf16), grid-strided.
// ---------------------------------------------------------------------------
__global__ void prep_weights(const float* __restrict__ W1, const float* __restrict__ W2,
                             unsigned short* __restrict__ W1t, unsigned short* __restrict__ W2t) {
    const int t0 = blockIdx.x * 256 + threadIdx.x;
    const int stride = gridDim.x * 256;
    for (int i = t0; i < HDIM * FDIM; i += stride) {
        const int n = i >> 7, k = i & 127;
        W1t[i] = f2bf(W1[k * HDIM + n]);
    }
    for (int i = t0; i < HDIM * HDIM; i += stride) {
        const int n = i >> 6, k = i & 63;
        W2t[i] = f2bf(W2[k * HDIM + n]);
    }
}

// ---------------------------------------------------------------------------
// Kernel 0b: Wm1t[n][k] = bf16(Wm1[k][n]), n<256, k<4224. Tiled 32x32 via LDS.
// ---------------------------------------------------------------------------
__global__ __launch_bounds__(256)
void prep_wm1(const float* __restrict__ Wm1, unsigned short* __restrict__ Wm1t) {
    __shared__ float tile[32][33];
    const int k0 = blockIdx.x * 32, n0 = blockIdx.y * 32;
    const int t = threadIdx.x;
    const int c = t & 31, r8 = t >> 5;
    #pragma unroll
    for (int rr = r8; rr < 32; rr += 8)
        tile[rr][c] = Wm1[(size_t)(k0 + rr) * MDIM + n0 + c];
    __syncthreads();
    #pragma unroll
    for (int j = 0; j < 4; ++j) {
        const int n = n0 + r8 + 8 * j;
        Wm1t[(size_t)n * KTOT + k0 + c] = f2bf(tile[c][r8 + 8 * j]);
    }
}

#define WAITLDS() do { __asm__ volatile("s_waitcnt lgkmcnt(0)" ::: "memory"); \
                       __builtin_amdgcn_sched_barrier(0); } while (0)

// ---------------------------------------------------------------------------
// Kernel 1: per-graph GCN encoder — ONE GRAPH PER WAVE, 64-thread blocks,
// ZERO barriers (wave-synchronous; in-wave lgkmcnt ordering only).
// LDS 24576 B/block -> 6 blocks/CU. Layout (bytes):
//   [    0, 8192)  Ab  bf16[64][64] swizzled (live whole kernel)
//   [ 8192,16384)  T1t (step1->2), then T3t (step3->4)
//   [16384,24576)  T2b (step2->3)
//   overlays (dead before first T-write): cnt u32[64][33] at [8192,16640);
//   deg[64] at [16640,16896); nrm[64] at [16896,17152)
// ---------------------------------------------------------------------------
__global__ __launch_bounds__(64, 2)
void encode_kernel(const float* __restrict__ x1, const float* __restrict__ x2,
                   const int* __restrict__ e1, const int* __restrict__ e2,
                   const unsigned short* __restrict__ W1t, const float* __restrict__ b1,
                   const unsigned short* __restrict__ W2t, const float* __restrict__ b2,
                   float* __restrict__ hbuf) {
    __shared__ __align__(16) unsigned char lds[24576];
    const int gid  = blockIdx.x;                  // 0..8191 = one graph
    const int drug = gid >> 12;
    const int b    = gid & (B_PAIRS - 1);
    const float* x  = (drug ? x2 : x1) + (size_t)b * NNODES * FDIM;
    const int*   eg = (drug ? e2 : e1) + (size_t)b * 2 * NEDGES;

    const int t  = threadIdx.x;                   // lane 0..63
    const int lr = t & 15, lg = t >> 4;
    const unsigned swl = (unsigned)(lr & 7) << 4; // row swizzle (rows ≡ lr mod 8)

    unsigned* cnt = (unsigned*)(lds + 8192);
    int*      deg = (int*)(lds + 16640);
    float*    nrm = (float*)(lds + 16896);

    // ---- fire ALL x A-fragment loads (32 x float4 = this wave's whole graph) ----
    float4 xa[32];
    #pragma unroll
    for (int mt = 0; mt < 4; ++mt) {
        const float* xr = x + (size_t)(16 * mt + lr) * FDIM + 8 * lg;
        #pragma unroll
        for (int ks = 0; ks < 4; ++ks) {
            xa[mt * 8 + 2 * ks]     = ((const float4*)(xr + 32 * ks))[0];
            xa[mt * 8 + 2 * ks + 1] = ((const float4*)(xr + 32 * ks))[1];
        }
    }
    // edges straight to registers (4 edges/lane)
    const int4 s4 = ((const int4*)eg)[t];
    const int4 d4 = ((const int4*)eg)[t + 64];

    // ---- zero cnt (2112 u32) + deg ----
    #pragma unroll
    for (int i = 0; i < 8; ++i) ((uint4*)cnt)[t + 64 * i] = make_uint4(0, 0, 0, 0);
    if (t < 16) ((uint4*)cnt)[512 + t] = make_uint4(0, 0, 0, 0);
    deg[t] = 0;
    WAITLDS();

    // ---- degree + multiplicity atomics (this wave only) ----
    {
        const int ss[4] = {s4.x, s4.y, s4.z, s4.w};
        const int dd[4] = {d4.x, d4.y, d4.z, d4.w};
        #pragma unroll
        for (int i = 0; i < 4; ++i) {
            atomicAdd(&deg[dd[i]], 1);
            atomicAdd(&cnt[dd[i] * 33 + (ss[i] >> 1)], 1u << ((ss[i] & 1) * 16));
        }
    }
    WAITLDS();
    nrm[t] = rsqrtf((float)deg[t] + 1.0f);
    WAITLDS();

    // hoist step-1 W1t B-fragments (L2-hot) to overlap with A-hat build
    bf16x8 bw1[16];
    #pragma unroll
    for (int nt = 0; nt < 4; ++nt)
        #pragma unroll
        for (int ks = 0; ks < 4; ++ks)
            bw1[nt * 4 + ks] = *(const bf16x8*)(W1t + (16 * nt + lr) * FDIM + 32 * ks + 8 * lg);

    // ---- build A-hat (lane t builds row t) ----
    {
        const int r = t;
        const float nr = nrm[r];
        unsigned char* arow = lds + r * 128;
        const unsigned sw = (unsigned)(r & 7) << 4;
        #pragma unroll
        for (int cw = 0; cw < 16; ++cw) {
            const unsigned w0 = cnt[r * 33 + 2 * cw];
            const unsigned w1 = cnt[r * 33 + 2 * cw + 1];
            const float4 nv = ((const float4*)nrm)[cw];
            const int c = 4 * cw;
            const float u0 = (float)((w0 & 0xffffu) + (r == c     ? 1u : 0u)) * nr * nv.x;
            const float u1 = (float)((w0 >> 16)     + (r == c + 1 ? 1u : 0u)) * nr * nv.y;
            const float u2 = (float)((w1 & 0xffffu) + (r == c + 2 ? 1u : 0u)) * nr * nv.z;
            const float u3 = (float)((w1 >> 16)     + (r == c + 3 ? 1u : 0u)) * nr * nv.w;
            *(unsigned long long*)(arow + (((unsigned)(8 * cw)) ^ sw)) = pack4(u0, u1, u2, u3);
        }
    }
    WAITLDS();                                    // cnt dead from here

    // ---- step1: T1 = X @ W1 -> T1t[featH][node] at 8192 ----
    #pragma unroll
    for (int mt = 0; mt < 4; ++mt) {
        f32x4 acc[4];
        #pragma unroll
        for (int nt = 0; nt < 4; ++nt) acc[nt] = (f32x4){0.f, 0.f, 0.f, 0.f};
        #pragma unroll
        for (int ks = 0; ks < 4; ++ks) {
            bf16x8 a;
            const float4 u = xa[mt * 8 + 2 * ks], v = xa[mt * 8 + 2 * ks + 1];
            a[0] = (__bf16)u.x; a[1] = (__bf16)u.y; a[2] = (__bf16)u.z; a[3] = (__bf16)u.w;
            a[4] = (__bf16)v.x; a[5] = (__bf16)v.y; a[6] = (__bf16)v.z; a[7] = (__bf16)v.w;
            #pragma unroll
            for (int nt = 0; nt < 4; ++nt)
                acc[nt] = __builtin_amdgcn_mfma_f32_16x16x32_bf16(a, bw1[nt * 4 + ks], acc[nt], 0, 0, 0);
        }
        const unsigned m2 = (unsigned)(2 * (16 * mt + 4 * lg));
        #pragma unroll
        for (int nt = 0; nt < 4; ++nt) {
            const int f = 16 * nt + lr;
            *(unsigned long long*)(lds + 8192u + (unsigned)f * 128 + (m2 ^ swl)) =
                pack4(acc[nt][0], acc[nt][1], acc[nt][2], acc[nt][3]);
        }
    }
    WAITLDS();

    // ---- step2: T2^T = T1t @ A^T (+b1, relu) -> T2b[node][featH] at 16384 ----
    {
        bf16x8 ba[8];
        #pragma unroll
        for (int nt = 0; nt < 4; ++nt)
            #pragma unroll
            for (int ks = 0; ks < 2; ++ks)
                ba[nt * 2 + ks] = *(const bf16x8*)(lds + (unsigned)(16 * nt + lr) * 128 +
                                                   (((unsigned)(64 * ks + 16 * lg)) ^ swl));
        #pragma unroll
        for (int mt = 0; mt < 4; ++mt) {
            f32x4 acc[4];
            #pragma unroll
            for (int nt = 0; nt < 4; ++nt) acc[nt] = (f32x4){0.f, 0.f, 0.f, 0.f};
            #pragma unroll
            for (int ks = 0; ks < 2; ++ks) {
                const bf16x8 a = *(const bf16x8*)(lds + 8192u + (unsigned)(16 * mt + lr) * 128 +
                                                  (((unsigned)(64 * ks + 16 * lg)) ^ swl));
                #pragma unroll
                for (int nt = 0; nt < 4; ++nt)
                    acc[nt] = __builtin_amdgcn_mfma_f32_16x16x32_bf16(a, ba[nt * 2 + ks], acc[nt], 0, 0, 0);
            }
            const int m0 = 16 * mt + 4 * lg;
            const float4 b1v = *(const float4*)(b1 + m0);
            const unsigned m2 = (unsigned)(2 * m0);
            #pragma unroll
            for (int nt = 0; nt < 4; ++nt) {
                const int d = 16 * nt + lr;
                const float v0 = fmaxf(acc[nt][0] + b1v.x, 0.f);
                const float v1 = fmaxf(acc[nt][1] + b1v.y, 0.f);
                const float v2 = fmaxf(acc[nt][2] + b1v.z, 0.f);
                const float v3 = fmaxf(acc[nt][3] + b1v.w, 0.f);
                *(unsigned long long*)(lds + 16384u + (unsigned)d * 128 + (m2 ^ swl)) =
                    pack4(v0, v1, v2, v3);
            }
        }
    }
    WAITLDS();

    // ---- step3: T3 = T2b @ W2 -> T3t[outH][node] at 8192 ----
    {
        bf16x8 bw2[8];
        #pragma unroll
        for (int nt = 0; nt < 4; ++nt)
            #pragma unroll
            for (int ks = 0; ks < 2; ++ks)
                bw2[nt * 2 + ks] = *(const bf16x8*)(W2t + (16 * nt + lr) * HDIM + 32 * ks + 8 * lg);
        #pragma unroll
        for (int mt = 0; mt < 4; ++mt) {
            f32x4 acc[4];
            #pragma unroll
            for (int nt = 0; nt < 4; ++nt) acc[nt] = (f32x4){0.f, 0.f, 0.f, 0.f};
            #pragma unroll
            for (int ks = 0; ks < 2; ++ks) {
                const bf16x8 a = *(const bf16x8*)(lds + 16384u + (unsigned)(16 * mt + lr) * 128 +
                                                  (((unsigned)(64 * ks + 16 * lg)) ^ swl));
                #pragma unroll
                for (int nt = 0; nt < 4; ++nt)
                    acc[nt] = __builtin_amdgcn_mfma_f32_16x16x32_bf16(a, bw2[nt * 2 + ks], acc[nt], 0, 0, 0);
            }
            const unsigned m2 = (unsigned)(2 * (16 * mt + 4 * lg));
            #pragma unroll
            for (int nt = 0; nt < 4; ++nt) {
                const int n = 16 * nt + lr;
                *(unsigned long long*)(lds + 8192u + (unsigned)n * 128 + (m2 ^ swl)) =
                    pack4(acc[nt][0], acc[nt][1], acc[nt][2], acc[nt][3]);
            }
        }
    }
    WAITLDS();

    // ---- step4: h2 = Ab @ T3 (+b2, relu), pool over nodes ----
    {
        bf16x8 bt3[8];
        #pragma unroll
        for (int nt = 0; nt < 4; ++nt)
            #pragma unroll
            for (int ks = 0; ks < 2; ++ks)
                bt3[nt * 2 + ks] = *(const bf16x8*)(lds + 8192u + (unsigned)(16 * nt + lr) * 128 +
                                                    (((unsigned)(64 * ks + 16 * lg)) ^ swl));
        float b2v[4], p[4];
        #pragma unroll
        for (int nt = 0; nt < 4; ++nt) { b2v[nt] = b2[16 * nt + lr]; p[nt] = 0.f; }
        #pragma unroll
        for (int mt = 0; mt < 4; ++mt) {
            f32x4 acc[4];
            #pragma unroll
            for (int nt = 0; nt < 4; ++nt) acc[nt] = (f32x4){0.f, 0.f, 0.f, 0.f};
            #pragma unroll
            for (int ks = 0; ks < 2; ++ks) {
                const bf16x8 a = *(const bf16x8*)(lds + (unsigned)(16 * mt + lr) * 128 +
                                                  (((unsigned)(64 * ks + 16 * lg)) ^ swl));
                #pragma unroll
                for (int nt = 0; nt < 4; ++nt)
                    acc[nt] = __builtin_amdgcn_mfma_f32_16x16x32_bf16(a, bt3[nt * 2 + ks], acc[nt], 0, 0, 0);
            }
            #pragma unroll
            for (int nt = 0; nt < 4; ++nt) {
                #pragma unroll
                for (int j = 0; j < 4; ++j) p[nt] += fmaxf(acc[nt][j] + b2v[nt], 0.f);
            }
        }
        #pragma unroll
        for (int nt = 0; nt < 4; ++nt) {
            p[nt] += __shfl_xor(p[nt], 16, 64);
            p[nt] += __shfl_xor(p[nt], 32, 64);
        }
        if (lg == 0) {
            float* hout = hbuf + ((size_t)drug * B_PAIRS + b) * HDIM;
            #pragma unroll
            for (int nt = 0; nt < 4; ++nt) hout[16 * nt + lr] = p[nt] * (1.0f / 64.0f);
        }
    }
}

// ---------------------------------------------------------------------------
// Kernel 2: fused MLP (reverted to R5's proven version).
// hidden = relu([h1|h2|fp1|fp2] @ Wm1 + bm1); out = sigmoid(hidden.Wm2 + bm2)
// 16 pairs/block, 256 threads, 256 blocks; double-buffered A tile.
// ---------------------------------------------------------------------------
__global__ __launch_bounds__(256)
void fused_mlp_kernel(const float* __restrict__ fp1, const float* __restrict__ fp2,
                      const float* __restrict__ hbuf,
                      const unsigned short* __restrict__ Wm1t,  // [256][4224] bf16
                      const float* __restrict__ bm1, const float* __restrict__ Wm2,
                      const float* __restrict__ bm2, float* __restrict__ out) {
    __shared__ __align__(16) unsigned char lds[8448];
    float* pool = (float*)(lds + 8192);            // 64 floats
    const int t = threadIdx.x;
    const int lane = t & 63, wid = t >> 6;
    const int lr = lane & 15, lg = lane >> 4;
    const int pair0 = blockIdx.x * 16;

    const int r  = t >> 4;                         // staging pair row 0..15
    const int kc = (t & 15) << 3;                  // staging k-offset (floats)
    const int pr = pair0 + r;
    const unsigned wOff = (unsigned)r * 256 + (((unsigned)(2 * kc)) ^ ((unsigned)(r & 7) << 4));

    f32x4 acc[4];
    #pragma unroll
    for (int nf = 0; nf < 4; ++nf) acc[nf] = (f32x4){0.f, 0.f, 0.f, 0.f};

    const unsigned short* brow[4];
    #pragma unroll
    for (int nf = 0; nf < 4; ++nf)
        brow[nf] = Wm1t + (size_t)(64 * wid + 16 * nf + lr) * KTOT + 8 * lg;

    float4 va, vb;
    #define LOAD_A(s)                                                                  \
        {                                                                              \
            const float* src;                                                          \
            if ((s) == 0)                                                              \
                src = (kc < 64) ? hbuf + (size_t)pr * HDIM + kc                        \
                                : hbuf + (size_t)(B_PAIRS + pr) * HDIM + (kc - 64);    \
            else if ((s) <= 16)                                                        \
                src = fp1 + (size_t)pr * FPDIM + ((s) - 1) * 128 + kc;                 \
            else                                                                       \
                src = fp2 + (size_t)pr * FPDIM + ((s) - 17) * 128 + kc;                \
            va = ((const float4*)src)[0];                                              \
            vb = ((const float4*)src)[1];                                              \
        }
    #define STORE_A(base)                                                              \
        *(uint4*)((base) + wOff) = make_uint4(pack2(va.x, va.y), pack2(va.z, va.w),    \
                                              pack2(vb.x, vb.y), pack2(vb.z, vb.w));

    LOAD_A(0);
    STORE_A(lds);
    for (int s = 0; s < 33; ++s) {
        const bool more = (s + 1 < 33);
        if (more) LOAD_A(s + 1);                   // issue next-step globals early
        __syncthreads();                           // buf[s&1] ready; prev reads drained
        const unsigned char* buf = lds + (unsigned)((s & 1) << 12);
        const unsigned asw = (unsigned)(lr & 7) << 4;
        const int kglob = s << 7;
        #pragma unroll
        for (int ks = 0; ks < 4; ++ks) {
            const unsigned kb = (unsigned)(64 * ks + 16 * lg);
            const bf16x8 a = *(const bf16x8*)(buf + (unsigned)lr * 256 + (kb ^ asw));
            #pragma unroll
            for (int nf = 0; nf < 4; ++nf) {
                const bf16x8 bw = *(const bf16x8*)(brow[nf] + kglob + 32 * ks);
                acc[nf] = __builtin_amdgcn_mfma_f32_16x16x32_bf16(a, bw, acc[nf], 0, 0, 0);
            }
        }
        if (more) STORE_A(lds + (unsigned)(((s + 1) & 1) << 12));
    }

    // epilogue: bias, relu, dot Wm2, reduce over n, sigmoid
    float bm1v[4], wm2v[4];
    #pragma unroll
    for (int nf = 0; nf < 4; ++nf) {
        const int n = 64 * wid + 16 * nf + lr;
        bm1v[nf] = bm1[n];
        wm2v[nf] = Wm2[n];
    }
    #pragma unroll
    for (int reg = 0; reg < 4; ++reg) {            // row m = 4*lg + reg
        float p = 0.f;
        #pragma unroll
        for (int nf = 0; nf < 4; ++nf)
            p += fmaxf(acc[nf][reg] + bm1v[nf], 0.f) * wm2v[nf];
        p += __shfl_xor(p, 1, 64);
        p += __shfl_xor(p, 2, 64);
        p += __shfl_xor(p, 4, 64);
        p += __shfl_xor(p, 8, 64);
        if (lr == 0) pool[wid * 16 + 4 * lg + reg] = p;
    }
    __syncthreads();
    if (t < 16) {
        const float y = pool[t] + pool[16 + t] + pool[32 + t] + pool[48 + t] + bm2[0];
        out[pair0 + t] = 1.0f / (1.0f + expf(-y));
    }
    #undef LOAD_A
    #undef STORE_A
}

extern "C" void kernel_launch(void* const* d_in, const int* in_sizes, int n_in,
                              void* d_out, int out_size, void* d_ws, size_t ws_size,
                              hipStream_t stream) {
    const float* x1  = (const float*)d_in[0];
    const float* x2  = (const float*)d_in[1];
    const int*   e1  = (const int*)d_in[2];
    const int*   e2  = (const int*)d_in[3];
    const float* fp1 = (const float*)d_in[4];
    const float* fp2 = (const float*)d_in[5];
    const float* W1  = (const float*)d_in[6];
    const float* b1  = (const float*)d_in[7];
    const float* W2  = (const float*)d_in[8];
    const float* b2  = (const float*)d_in[9];
    const float* Wm1 = (const float*)d_in[10];
    const float* bm1 = (const float*)d_in[11];
    const float* Wm2 = (const float*)d_in[12];
    const float* bm2 = (const float*)d_in[13];
    float* out  = (float*)d_out;

    float* hbuf = (float*)d_ws;                                          // 2 MB
    unsigned short* W1t  = (unsigned short*)((char*)d_ws + (2 << 20));   // 16 KB
    unsigned short* W2t  = W1t + HDIM * FDIM;                            // 8 KB
    unsigned short* Wm1t = (unsigned short*)((char*)d_ws + (3 << 20));   // 2.16 MB

    hipLaunchKernelGGL(prep_weights, dim3(16), dim3(256), 0, stream, W1, W2, W1t, W2t);
    hipLaunchKernelGGL(prep_wm1, dim3(132, 8), dim3(256), 0, stream, Wm1, Wm1t);
    hipLaunchKernelGGL(encode_kernel, dim3(2 * B_PAIRS), dim3(64), 0, stream,
                       x1, x2, e1, e2, W1t, b1, W2t, b2, hbuf);
    hipLaunchKernelGGL(fused_mlp_kernel, dim3(B_PAIRS / 16), dim3(256), 0, stream,
                       fp1, fp2, hbuf, Wm1t, bm1, Wm2, bm2, out);
}

// Round 8
// 162.293 us; speedup vs baseline: 1.4333x; 1.0483x over previous
//
#include <hip/hip_runtime.h>
#include <math.h>

#define B_PAIRS 4096
#define NNODES  64
#define NEDGES  256
#define FDIM    128
#define HDIM    64
#define FPDIM   2048
#define MDIM    256
#define KTOT    4224   // 2*HDIM + 2*FPDIM

typedef __attribute__((ext_vector_type(4))) float f32x4;
typedef __bf16 bf16x8 __attribute__((ext_vector_type(8)));

__device__ __forceinline__ unsigned short f2bf(float f) {
    return __builtin_bit_cast(unsigned short, (__bf16)f);
}
__device__ __forceinline__ unsigned pack2(float a, float b) {
    return (unsigned)f2bf(a) | ((unsigned)f2bf(b) << 16);
}
__device__ __forceinline__ unsigned long long pack4(float a, float b, float c, float d) {
    return (unsigned long long)pack2(a, b) | ((unsigned long long)pack2(c, d) << 32);
}

// ---------------------------------------------------------------------------
// Kernel 0a: W1t[n][k]=W1[k][n], W2t[n][k]=W2[k][n] (bf16), grid-strided.
// ---------------------------------------------------------------------------
__global__ void prep_weights(const float* __restrict__ W1, const float* __restrict__ W2,
                             unsigned short* __restrict__ W1t, unsigned short* __restrict__ W2t) {
    const int t0 = blockIdx.x * 256 + threadIdx.x;
    const int stride = gridDim.x * 256;
    for (int i = t0; i < HDIM * FDIM; i += stride) {
        const int n = i >> 7, k = i & 127;
        W1t[i] = f2bf(W1[k * HDIM + n]);
    }
    for (int i = t0; i < HDIM * HDIM; i += stride) {
        const int n = i >> 6, k = i & 63;
        W2t[i] = f2bf(W2[k * HDIM + n]);
    }
}

// ---------------------------------------------------------------------------
// Kernel 0b: Wm1t[n][k] = bf16(Wm1[k][n]), n<256, k<4224. Tiled 32x32 via LDS.
// ---------------------------------------------------------------------------
__global__ __launch_bounds__(256)
void prep_wm1(const float* __restrict__ Wm1, unsigned short* __restrict__ Wm1t) {
    __shared__ float tile[32][33];
    const int k0 = blockIdx.x * 32, n0 = blockIdx.y * 32;
    const int t = threadIdx.x;
    const int c = t & 31, r8 = t >> 5;
    #pragma unroll
    for (int rr = r8; rr < 32; rr += 8)
        tile[rr][c] = Wm1[(size_t)(k0 + rr) * MDIM + n0 + c];
    __syncthreads();
    #pragma unroll
    for (int j = 0; j < 4; ++j) {
        const int n = n0 + r8 + 8 * j;
        Wm1t[(size_t)n * KTOT + k0 + c] = f2bf(tile[c][r8 + 8 * j]);
    }
}

#define WAITLDS() do { __asm__ volatile("s_waitcnt lgkmcnt(0)" ::: "memory"); \
                       __builtin_amdgcn_sched_barrier(0); } while (0)

// ---------------------------------------------------------------------------
// Kernel 1: per-graph GCN encoder — one graph per wave, zero barriers,
// SINGLE shared temp buffer (register-preload before overwrite).
// LDS 17152 B/block -> 9 blocks/CU (was 24576 -> 6). Layout (bytes):
//   [    0, 8192)  Ab  bf16[64][64] swizzled (live whole kernel)
//   [ 8192,16384)  temp: T1t -> T2b -> T3t (each preloaded to regs before
//                  being overwritten by the next step's output)
//   overlays: cnt u32[64][33] at [8192,16640) (dead before step1 writes);
//   nrm[64] at [16640,16896); deg[64] at [16896,17152)
// ---------------------------------------------------------------------------
__global__ __launch_bounds__(64, 2)
void encode_kernel(const float* __restrict__ x1, const float* __restrict__ x2,
                   const int* __restrict__ e1, const int* __restrict__ e2,
                   const unsigned short* __restrict__ W1t, const float* __restrict__ b1,
                   const unsigned short* __restrict__ W2t, const float* __restrict__ b2,
                   float* __restrict__ hbuf) {
    __shared__ __align__(16) unsigned char lds[17152];
    const int gid  = blockIdx.x;                  // 0..8191 = one graph
    const int drug = gid >> 12;
    const int b    = gid & (B_PAIRS - 1);
    const float* x  = (drug ? x2 : x1) + (size_t)b * NNODES * FDIM;
    const int*   eg = (drug ? e2 : e1) + (size_t)b * 2 * NEDGES;

    const int t  = threadIdx.x;                   // lane 0..63
    const int lr = t & 15, lg = t >> 4;
    const unsigned swl = (unsigned)(lr & 7) << 4; // row swizzle (rows ≡ lr mod 8)

    unsigned* cnt = (unsigned*)(lds + 8192);
    float*    nrm = (float*)(lds + 16640);
    int*      deg = (int*)(lds + 16896);

    // ---- fire first half of x loads (mt 0,1) ----
    float4 xalo[16];
    #pragma unroll
    for (int mt = 0; mt < 2; ++mt) {
        const float* xr = x + (size_t)(16 * mt + lr) * FDIM + 8 * lg;
        #pragma unroll
        for (int ks = 0; ks < 4; ++ks) {
            xalo[mt * 8 + 2 * ks]     = ((const float4*)(xr + 32 * ks))[0];
            xalo[mt * 8 + 2 * ks + 1] = ((const float4*)(xr + 32 * ks))[1];
        }
    }
    // edges straight to registers (4 edges/lane)
    const int4 s4 = ((const int4*)eg)[t];
    const int4 d4 = ((const int4*)eg)[t + 64];

    // ---- zero cnt (2112 u32) + deg ----
    #pragma unroll
    for (int i = 0; i < 8; ++i) ((uint4*)cnt)[t + 64 * i] = make_uint4(0, 0, 0, 0);
    if (t < 16) ((uint4*)cnt)[512 + t] = make_uint4(0, 0, 0, 0);
    deg[t] = 0;
    WAITLDS();

    // ---- degree + multiplicity atomics (this wave only) ----
    {
        const int ss[4] = {s4.x, s4.y, s4.z, s4.w};
        const int dd[4] = {d4.x, d4.y, d4.z, d4.w};
        #pragma unroll
        for (int i = 0; i < 4; ++i) {
            atomicAdd(&deg[dd[i]], 1);
            atomicAdd(&cnt[dd[i] * 33 + (ss[i] >> 1)], 1u << ((ss[i] & 1) * 16));
        }
    }
    WAITLDS();

    // ---- fire second half of x loads (mt 2,3) — pinned here by sched_barrier
    float4 xahi[16];
    #pragma unroll
    for (int mt = 0; mt < 2; ++mt) {
        const float* xr = x + (size_t)(16 * (mt + 2) + lr) * FDIM + 8 * lg;
        #pragma unroll
        for (int ks = 0; ks < 4; ++ks) {
            xahi[mt * 8 + 2 * ks]     = ((const float4*)(xr + 32 * ks))[0];
            xahi[mt * 8 + 2 * ks + 1] = ((const float4*)(xr + 32 * ks))[1];
        }
    }

    nrm[t] = rsqrtf((float)deg[t] + 1.0f);
    WAITLDS();

    // hoist step-1 W1t B-fragments (L2-hot) to overlap with A-hat build
    bf16x8 bw1[16];
    #pragma unroll
    for (int nt = 0; nt < 4; ++nt)
        #pragma unroll
        for (int ks = 0; ks < 4; ++ks)
            bw1[nt * 4 + ks] = *(const bf16x8*)(W1t + (16 * nt + lr) * FDIM + 32 * ks + 8 * lg);

    // ---- build A-hat (lane t builds row t) ----
    {
        const int r = t;
        const float nr = nrm[r];
        unsigned char* arow = lds + r * 128;
        const unsigned sw = (unsigned)(r & 7) << 4;
        #pragma unroll
        for (int cw = 0; cw < 16; ++cw) {
            const unsigned w0 = cnt[r * 33 + 2 * cw];
            const unsigned w1 = cnt[r * 33 + 2 * cw + 1];
            const float4 nv = ((const float4*)nrm)[cw];
            const int c = 4 * cw;
            const float u0 = (float)((w0 & 0xffffu) + (r == c     ? 1u : 0u)) * nr * nv.x;
            const float u1 = (float)((w0 >> 16)     + (r == c + 1 ? 1u : 0u)) * nr * nv.y;
            const float u2 = (float)((w1 & 0xffffu) + (r == c + 2 ? 1u : 0u)) * nr * nv.z;
            const float u3 = (float)((w1 >> 16)     + (r == c + 3 ? 1u : 0u)) * nr * nv.w;
            *(unsigned long long*)(arow + (((unsigned)(8 * cw)) ^ sw)) = pack4(u0, u1, u2, u3);
        }
    }
    WAITLDS();                                    // cnt dead from here

    // ---- step1: T1 = X @ W1 -> T1t[featH][node] at temp (8192) ----
    #pragma unroll
    for (int half = 0; half < 2; ++half) {
        const float4* xs = half ? xahi : xalo;
        #pragma unroll
        for (int m2i = 0; m2i < 2; ++m2i) {
            const int mt = half * 2 + m2i;
            f32x4 acc[4];
            #pragma unroll
            for (int nt = 0; nt < 4; ++nt) acc[nt] = (f32x4){0.f, 0.f, 0.f, 0.f};
            #pragma unroll
            for (int ks = 0; ks < 4; ++ks) {
                bf16x8 a;
                const float4 u = xs[m2i * 8 + 2 * ks], v = xs[m2i * 8 + 2 * ks + 1];
                a[0] = (__bf16)u.x; a[1] = (__bf16)u.y; a[2] = (__bf16)u.z; a[3] = (__bf16)u.w;
                a[4] = (__bf16)v.x; a[5] = (__bf16)v.y; a[6] = (__bf16)v.z; a[7] = (__bf16)v.w;
                #pragma unroll
                for (int nt = 0; nt < 4; ++nt)
                    acc[nt] = __builtin_amdgcn_mfma_f32_16x16x32_bf16(a, bw1[nt * 4 + ks], acc[nt], 0, 0, 0);
            }
            const unsigned m2 = (unsigned)(2 * (16 * mt + 4 * lg));
            #pragma unroll
            for (int nt = 0; nt < 4; ++nt) {
                const int f = 16 * nt + lr;
                *(unsigned long long*)(lds + 8192u + (unsigned)f * 128 + (m2 ^ swl)) =
                    pack4(acc[nt][0], acc[nt][1], acc[nt][2], acc[nt][3]);
            }
        }
    }
    WAITLDS();                                    // T1t visible

    // ---- step2: T2^T = T1t @ A^T (+b1, relu) -> T2b OVER temp ----
    {
        // preload all T1t A-fragments (about to be overwritten) + Ab B-frags
        bf16x8 ta[8], ba[8];
        #pragma unroll
        for (int mt = 0; mt < 4; ++mt)
            #pragma unroll
            for (int ks = 0; ks < 2; ++ks)
                ta[mt * 2 + ks] = *(const bf16x8*)(lds + 8192u + (unsigned)(16 * mt + lr) * 128 +
                                                   (((unsigned)(64 * ks + 16 * lg)) ^ swl));
        #pragma unroll
        for (int nt = 0; nt < 4; ++nt)
            #pragma unroll
            for (int ks = 0; ks < 2; ++ks)
                ba[nt * 2 + ks] = *(const bf16x8*)(lds + (unsigned)(16 * nt + lr) * 128 +
                                                   (((unsigned)(64 * ks + 16 * lg)) ^ swl));
        WAITLDS();                                // all reads done before overwrite
        #pragma unroll
        for (int mt = 0; mt < 4; ++mt) {
            f32x4 acc[4];
            #pragma unroll
            for (int nt = 0; nt < 4; ++nt) acc[nt] = (f32x4){0.f, 0.f, 0.f, 0.f};
            #pragma unroll
            for (int ks = 0; ks < 2; ++ks) {
                #pragma unroll
                for (int nt = 0; nt < 4; ++nt)
                    acc[nt] = __builtin_amdgcn_mfma_f32_16x16x32_bf16(ta[mt * 2 + ks], ba[nt * 2 + ks], acc[nt], 0, 0, 0);
            }
            const int m0 = 16 * mt + 4 * lg;
            const float4 b1v = *(const float4*)(b1 + m0);
            const unsigned m2 = (unsigned)(2 * m0);
            #pragma unroll
            for (int nt = 0; nt < 4; ++nt) {
                const int d = 16 * nt + lr;
                const float v0 = fmaxf(acc[nt][0] + b1v.x, 0.f);
                const float v1 = fmaxf(acc[nt][1] + b1v.y, 0.f);
                const float v2 = fmaxf(acc[nt][2] + b1v.z, 0.f);
                const float v3 = fmaxf(acc[nt][3] + b1v.w, 0.f);
                *(unsigned long long*)(lds + 8192u + (unsigned)d * 128 + (m2 ^ swl)) =
                    pack4(v0, v1, v2, v3);
            }
        }
    }
    WAITLDS();                                    // T2b visible

    // ---- step3: T3 = T2b @ W2 -> T3t OVER temp ----
    {
        bf16x8 ta[8], bw2[8];
        #pragma unroll
        for (int mt = 0; mt < 4; ++mt)
            #pragma unroll
            for (int ks = 0; ks < 2; ++ks)
                ta[mt * 2 + ks] = *(const bf16x8*)(lds + 8192u + (unsigned)(16 * mt + lr) * 128 +
                                                   (((unsigned)(64 * ks + 16 * lg)) ^ swl));
        #pragma unroll
        for (int nt = 0; nt < 4; ++nt)
            #pragma unroll
            for (int ks = 0; ks < 2; ++ks)
                bw2[nt * 2 + ks] = *(const bf16x8*)(W2t + (16 * nt + lr) * HDIM + 32 * ks + 8 * lg);
        WAITLDS();                                // T2b reads done before overwrite
        #pragma unroll
        for (int mt = 0; mt < 4; ++mt) {
            f32x4 acc[4];
            #pragma unroll
            for (int nt = 0; nt < 4; ++nt) acc[nt] = (f32x4){0.f, 0.f, 0.f, 0.f};
            #pragma unroll
            for (int ks = 0; ks < 2; ++ks) {
                #pragma unroll
                for (int nt = 0; nt < 4; ++nt)
                    acc[nt] = __builtin_amdgcn_mfma_f32_16x16x32_bf16(ta[mt * 2 + ks], bw2[nt * 2 + ks], acc[nt], 0, 0, 0);
            }
            const unsigned m2 = (unsigned)(2 * (16 * mt + 4 * lg));
            #pragma unroll
            for (int nt = 0; nt < 4; ++nt) {
                const int n = 16 * nt + lr;
                *(unsigned long long*)(lds + 8192u + (unsigned)n * 128 + (m2 ^ swl)) =
                    pack4(acc[nt][0], acc[nt][1], acc[nt][2], acc[nt][3]);
            }
        }
    }
    WAITLDS();                                    // T3t visible

    // ---- step4: h2 = Ab @ T3 (+b2, relu), pool over nodes ----
    {
        bf16x8 bt3[8];
        #pragma unroll
        for (int nt = 0; nt < 4; ++nt)
            #pragma unroll
            for (int ks = 0; ks < 2; ++ks)
                bt3[nt * 2 + ks] = *(const bf16x8*)(lds + 8192u + (unsigned)(16 * nt + lr) * 128 +
                                                    (((unsigned)(64 * ks + 16 * lg)) ^ swl));
        float b2v[4], p[4];
        #pragma unroll
        for (int nt = 0; nt < 4; ++nt) { b2v[nt] = b2[16 * nt + lr]; p[nt] = 0.f; }
        #pragma unroll
        for (int mt = 0; mt < 4; ++mt) {
            f32x4 acc[4];
            #pragma unroll
            for (int nt = 0; nt < 4; ++nt) acc[nt] = (f32x4){0.f, 0.f, 0.f, 0.f};
            #pragma unroll
            for (int ks = 0; ks < 2; ++ks) {
                const bf16x8 a = *(const bf16x8*)(lds + (unsigned)(16 * mt + lr) * 128 +
                                                  (((unsigned)(64 * ks + 16 * lg)) ^ swl));
                #pragma unroll
                for (int nt = 0; nt < 4; ++nt)
                    acc[nt] = __builtin_amdgcn_mfma_f32_16x16x32_bf16(a, bt3[nt * 2 + ks], acc[nt], 0, 0, 0);
            }
            #pragma unroll
            for (int nt = 0; nt < 4; ++nt) {
                #pragma unroll
                for (int j = 0; j < 4; ++j) p[nt] += fmaxf(acc[nt][j] + b2v[nt], 0.f);
            }
        }
        #pragma unroll
        for (int nt = 0; nt < 4; ++nt) {
            p[nt] += __shfl_xor(p[nt], 16, 64);
            p[nt] += __shfl_xor(p[nt], 32, 64);
        }
        if (lg == 0) {
            float* hout = hbuf + ((size_t)drug * B_PAIRS + b) * HDIM;
            #pragma unroll
            for (int nt = 0; nt < 4; ++nt) hout[16 * nt + lr] = p[nt] * (1.0f / 64.0f);
        }
    }
}

// ---------------------------------------------------------------------------
// Kernel 2: fused MLP (R5-proven version, unchanged).
// hidden = relu([h1|h2|fp1|fp2] @ Wm1 + bm1); out = sigmoid(hidden.Wm2 + bm2)
// 16 pairs/block, 256 threads, 256 blocks; double-buffered A tile.
// ---------------------------------------------------------------------------
__global__ __launch_bounds__(256)
void fused_mlp_kernel(const float* __restrict__ fp1, const float* __restrict__ fp2,
                      const float* __restrict__ hbuf,
                      const unsigned short* __restrict__ Wm1t,  // [256][4224] bf16
                      const float* __restrict__ bm1, const float* __restrict__ Wm2,
                      const float* __restrict__ bm2, float* __restrict__ out) {
    __shared__ __align__(16) unsigned char lds[8448];
    float* pool = (float*)(lds + 8192);            // 64 floats
    const int t = threadIdx.x;
    const int lane = t & 63, wid = t >> 6;
    const int lr = lane & 15, lg = lane >> 4;
    const int pair0 = blockIdx.x * 16;

    const int r  = t >> 4;                         // staging pair row 0..15
    const int kc = (t & 15) << 3;                  // staging k-offset (floats)
    const int pr = pair0 + r;
    const unsigned wOff = (unsigned)r * 256 + (((unsigned)(2 * kc)) ^ ((unsigned)(r & 7) << 4));

    f32x4 acc[4];
    #pragma unroll
    for (int nf = 0; nf < 4; ++nf) acc[nf] = (f32x4){0.f, 0.f, 0.f, 0.f};

    const unsigned short* brow[4];
    #pragma unroll
    for (int nf = 0; nf < 4; ++nf)
        brow[nf] = Wm1t + (size_t)(64 * wid + 16 * nf + lr) * KTOT + 8 * lg;

    float4 va, vb;
    #define LOAD_A(s)                                                                  \
        {                                                                              \
            const float* src;                                                          \
            if ((s) == 0)                                                              \
                src = (kc < 64) ? hbuf + (size_t)pr * HDIM + kc                        \
                                : hbuf + (size_t)(B_PAIRS + pr) * HDIM + (kc - 64);    \
            else if ((s) <= 16)                                                        \
                src = fp1 + (size_t)pr * FPDIM + ((s) - 1) * 128 + kc;                 \
            else                                                                       \
                src = fp2 + (size_t)pr * FPDIM + ((s) - 17) * 128 + kc;                \
            va = ((const float4*)src)[0];                                              \
            vb = ((const float4*)src)[1];                                              \
        }
    #define STORE_A(base)                                                              \
        *(uint4*)((base) + wOff) = make_uint4(pack2(va.x, va.y), pack2(va.z, va.w),    \
                                              pack2(vb.x, vb.y), pack2(vb.z, vb.w));

    LOAD_A(0);
    STORE_A(lds);
    for (int s = 0; s < 33; ++s) {
        const bool more = (s + 1 < 33);
        if (more) LOAD_A(s + 1);                   // issue next-step globals early
        __syncthreads();                           // buf[s&1] ready; prev reads drained
        const unsigned char* buf = lds + (unsigned)((s & 1) << 12);
        const unsigned asw = (unsigned)(lr & 7) << 4;
        const int kglob = s << 7;
        #pragma unroll
        for (int ks = 0; ks < 4; ++ks) {
            const unsigned kb = (unsigned)(64 * ks + 16 * lg);
            const bf16x8 a = *(const bf16x8*)(buf + (unsigned)lr * 256 + (kb ^ asw));
            #pragma unroll
            for (int nf = 0; nf < 4; ++nf) {
                const bf16x8 bw = *(const bf16x8*)(brow[nf] + kglob + 32 * ks);
                acc[nf] = __builtin_amdgcn_mfma_f32_16x16x32_bf16(a, bw, acc[nf], 0, 0, 0);
            }
        }
        if (more) STORE_A(lds + (unsigned)(((s + 1) & 1) << 12));
    }

    // epilogue: bias, relu, dot Wm2, reduce over n, sigmoid
    float bm1v[4], wm2v[4];
    #pragma unroll
    for (int nf = 0; nf < 4; ++nf) {
        const int n = 64 * wid + 16 * nf + lr;
        bm1v[nf] = bm1[n];
        wm2v[nf] = Wm2[n];
    }
    #pragma unroll
    for (int reg = 0; reg < 4; ++reg) {            // row m = 4*lg + reg
        float p = 0.f;
        #pragma unroll
        for (int nf = 0; nf < 4; ++nf)
            p += fmaxf(acc[nf][reg] + bm1v[nf], 0.f) * wm2v[nf];
        p += __shfl_xor(p, 1, 64);
        p += __shfl_xor(p, 2, 64);
        p += __shfl_xor(p, 4, 64);
        p += __shfl_xor(p, 8, 64);
        if (lr == 0) pool[wid * 16 + 4 * lg + reg] = p;
    }
    __syncthreads();
    if (t < 16) {
        const float y = pool[t] + pool[16 + t] + pool[32 + t] + pool[48 + t] + bm2[0];
        out[pair0 + t] = 1.0f / (1.0f + expf(-y));
    }
    #undef LOAD_A
    #undef STORE_A
}

extern "C" void kernel_launch(void* const* d_in, const int* in_sizes, int n_in,
                              void* d_out, int out_size, void* d_ws, size_t ws_size,
                              hipStream_t stream) {
    const float* x1  = (const float*)d_in[0];
    const float* x2  = (const float*)d_in[1];
    const int*   e1  = (const int*)d_in[2];
    const int*   e2  = (const int*)d_in[3];
    const float* fp1 = (const float*)d_in[4];
    const float* fp2 = (const float*)d_in[5];
    const float* W1  = (const float*)d_in[6];
    const float* b1  = (const float*)d_in[7];
    const float* W2  = (const float*)d_in[8];
    const float* b2  = (const float*)d_in[9];
    const float* Wm1 = (const float*)d_in[10];
    const float* bm1 = (const float*)d_in[11];
    const float* Wm2 = (const float*)d_in[12];
    const float* bm2 = (const float*)d_in[13];
    float* out  = (float*)d_out;

    float* hbuf = (float*)d_ws;                                          // 2 MB
    unsigned short* W1t  = (unsigned short*)((char*)d_ws + (2 << 20));   // 16 KB
    unsigned short* W2t  = W1t + HDIM * FDIM;                            // 8 KB
    unsigned short* Wm1t = (unsigned short*)((char*)d_ws + (3 << 20));   // 2.16 MB

    hipLaunchKernelGGL(prep_weights, dim3(16), dim3(256), 0, stream, W1, W2, W1t, W2t);
    hipLaunchKernelGGL(prep_wm1, dim3(132, 8), dim3(256), 0, stream, Wm1, Wm1t);
    hipLaunchKernelGGL(encode_kernel, dim3(2 * B_PAIRS), dim3(64), 0, stream,
                       x1, x2, e1, e2, W1t, b1, W2t, b2, hbuf);
    hipLaunchKernelGGL(fused_mlp_kernel, dim3(B_PAIRS / 16), dim3(256), 0, stream,
                       fp1, fp2, hbuf, Wm1t, bm1, Wm2, bm2, out);
}